// Round 1
// baseline (723.549 us; speedup 1.0000x reference)
//
#include <hip/hip_runtime.h>
#include <hip/hip_bf16.h>

#define HID 100
#define TT 750
#define NB_TOT 1024
#define ALPHA 0.01f
#define NSTD 0.1f

typedef __bf16 bf16x8 __attribute__((ext_vector_type(8)));
typedef float floatx4 __attribute__((ext_vector_type(4)));

__device__ __forceinline__ float fast_tanh(float v) {
    // tanh(v) = 1 - 2/(exp(2v)+1); graceful at +-inf, abs err ~1e-6
    float e = __expf(2.0f * v);
    return 1.0f - 2.0f / (e + 1.0f);
}

__global__ __launch_bounds__(256, 2)
void rnn_kernel(const float* __restrict__ useq,   // [750][1024][4]
                const float* __restrict__ noise,  // [750][1024][100]
                const float* __restrict__ Jw,     // [100][100]
                const float* __restrict__ Bm,     // [4][100]
                const float* __restrict__ cxp,    // [100]
                const float* __restrict__ Ww,     // [100]
                const float* __restrict__ Wb,     // [1]
                float* __restrict__ out)          // [1024]
{
    // r buffer: 16 rows (M) x 128 bf16 (K padded), 16B-chunk XOR swizzle
    __shared__ __align__(16) __bf16 rbuf[16 * 128];
    __shared__ float ybuf[2][112];
    __shared__ float red[256];

    const int tid  = threadIdx.x;
    const int wv   = tid >> 6;
    const int lane = tid & 63;
    const int wg   = blockIdx.x;

    // --- update-thread mapping: tid<200 -> (batch bb, hidden hh) ---
    const int  bb  = tid / 100;
    const int  hh  = tid % 100;
    const bool upd = (tid < 200);
    const int  gb  = wg * 2 + bb;   // global batch

    float bm0=0.f, bm1=0.f, bm2=0.f, bm3=0.f, cx=0.f, wout=0.f;
    if (upd) {
        bm0 = Bm[0*HID + hh]; bm1 = Bm[1*HID + hh];
        bm2 = Bm[2*HID + hh]; bm3 = Bm[3*HID + hh];
        cx  = cxp[hh];
        wout = Ww[hh];
    }

    // zero rbuf (rows 2..15 and k>=100 stay zero forever; also r_0 = tanh(0) = 0)
    {
        floatx4 z = {0.f, 0.f, 0.f, 0.f};
        ((floatx4*)rbuf)[tid] = z;
    }

    // --- preload J fragments (B-operand layout), split hi/lo bf16 ---
    // wave w owns N-tiles {2w, 2w+1}; tile 7 is a dummy (all zero, no writeback)
    const int m16 = lane & 15;
    const int q   = lane >> 4;
    bf16x8 jhi[2][4], jlo[2][4];
    #pragma unroll
    for (int ti = 0; ti < 2; ++ti) {
        const int tile = wv * 2 + ti;
        const int h = tile * 16 + m16;     // B n-index -> J row h
        #pragma unroll
        for (int s = 0; s < 4; ++s) {
            bf16x8 vhi, vlo;
            #pragma unroll
            for (int j = 0; j < 8; ++j) {
                const int k = s * 32 + q * 8 + j;
                float v = (h < HID && k < HID) ? Jw[h * HID + k] : 0.0f;
                __bf16 hi = (__bf16)v;
                vhi[j] = hi;
                vlo[j] = (__bf16)(v - (float)hi);
            }
            jhi[ti][s] = vhi;
            jlo[ti][s] = vlo;
        }
    }

    // --- prefetch pipeline (depth 4) for noise + input ---
    const float* np = noise + (size_t)gb * HID + hh;   // + t*102400
    const float* up = useq  + (size_t)gb * 4;          // + t*4096
    float   nb0=0.f, nb1=0.f, nb2=0.f, nb3=0.f;
    floatx4 ub0={0,0,0,0}, ub1={0,0,0,0}, ub2={0,0,0,0}, ub3={0,0,0,0};
    if (upd) {
        nb0 = np[0 * (NB_TOT*HID)]; ub0 = *(const floatx4*)(up + 0 * (NB_TOT*4));
        nb1 = np[1 * (NB_TOT*HID)]; ub1 = *(const floatx4*)(up + 1 * (NB_TOT*4));
        nb2 = np[2 * (NB_TOT*HID)]; ub2 = *(const floatx4*)(up + 2 * (NB_TOT*4));
        nb3 = np[3 * (NB_TOT*HID)]; ub3 = *(const floatx4*)(up + 3 * (NB_TOT*4));
    }

    float x = 0.0f;
    __syncthreads();

    auto step = [&](int T, float& NB, floatx4& UB) {
        // ---- Phase A: y_t = r_t @ J^T via MFMA ----
        bf16x8 afr[4];
        const bf16x8* rb16 = (const bf16x8*)rbuf;
        #pragma unroll
        for (int s = 0; s < 4; ++s)
            afr[s] = rb16[m16 * 16 + ((s * 4 + q) ^ (lane & 7))];
        #pragma unroll
        for (int ti = 0; ti < 2; ++ti) {
            floatx4 acc = {0.f, 0.f, 0.f, 0.f};
            #pragma unroll
            for (int s = 0; s < 4; ++s)
                acc = __builtin_amdgcn_mfma_f32_16x16x32_bf16(afr[s], jhi[ti][s], acc, 0, 0, 0);
            #pragma unroll
            for (int s = 0; s < 4; ++s)
                acc = __builtin_amdgcn_mfma_f32_16x16x32_bf16(afr[s], jlo[ti][s], acc, 0, 0, 0);
            const int tile = wv * 2 + ti;
            // C-layout: col = lane&15, row = (lane>>4)*4 + reg -> lanes 0..15 hold
            // rows 0..3 in regs 0..3; our batches are rows 0,1 -> regs 0,1.
            if (tile < 7 && lane < 16) {
                ybuf[0][tile * 16 + lane] = acc[0];
                ybuf[1][tile * 16 + lane] = acc[1];
            }
        }
        __syncthreads();
        // ---- Phase B: x_{t+1} = (1-a)x + a(y + drive + cx + 0.1 n); r = tanh(x) ----
        if (upd) {
            const float y = ybuf[bb][hh];
            const float d = UB[0]*bm0 + UB[1]*bm1 + UB[2]*bm2 + UB[3]*bm3;
            x = x * (1.0f - ALPHA) + ALPHA * (y + d + cx + NSTD * NB);
            const float r = fast_tanh(x);
            // A-layout write with chunk swizzle: chunk = hh>>3, xor with row (bb)
            rbuf[bb * 128 + (((hh >> 3) ^ bb) << 3) + (hh & 7)] = (__bf16)r;
            // prefetch t+4
            const int tf = (T + 4 < TT) ? (T + 4) : (TT - 1);
            NB = np[tf * (NB_TOT*HID)];
            UB = *(const floatx4*)(up + tf * (NB_TOT*4));
        }
        __syncthreads();
    };

    for (int tb = 0; tb < 748; tb += 4) {
        step(tb + 0, nb0, ub0);
        step(tb + 1, nb1, ub1);
        step(tb + 2, nb2, ub2);
        step(tb + 3, nb3, ub3);
    }
    step(748, nb0, ub0);
    step(749, nb1, ub1);

    // ---- epilogue: out[b] = sum_h tanh(x_final) * Wout[h] + Wout_b ----
    red[tid] = upd ? (fast_tanh(x) * wout) : 0.0f;
    __syncthreads();
    if (tid < 2) {
        float s2 = Wb[0];
        #pragma unroll 4
        for (int i = 0; i < HID; ++i) s2 += red[tid * HID + i];
        out[wg * 2 + tid] = s2;
    }
}

extern "C" void kernel_launch(void* const* d_in, const int* in_sizes, int n_in,
                              void* d_out, int out_size, void* d_ws, size_t ws_size,
                              hipStream_t stream) {
    rnn_kernel<<<dim3(512), dim3(256), 0, stream>>>(
        (const float*)d_in[0], (const float*)d_in[1], (const float*)d_in[2],
        (const float*)d_in[3], (const float*)d_in[4], (const float*)d_in[5],
        (const float*)d_in[6], (float*)d_out);
}